// Round 1
// baseline (28151.529 us; speedup 1.0000x reference)
//
#include <hip/hip_runtime.h>
#include <stdint.h>

#define LNUM 16
#define H 128
#define NN_IN 136
#define G4 512
#define K2N 132      // 264/2 packed f16 pairs
#define TT 64
#define NCLSN 30
#define EPSF 1e-6f

typedef _Float16 half2v __attribute__((ext_vector_type(2)));

__device__ inline float fdot2(uint32_t a, uint32_t b, float c) {
  return __builtin_amdgcn_fdot2(__builtin_bit_cast(half2v, a),
                                __builtin_bit_cast(half2v, b), c, false);
}
__device__ inline float sigf(float x) { return 1.0f / (1.0f + __expf(-x)); }
__device__ inline float softplusf(float x) {
  return fmaxf(x, 0.f) + log1pf(__expf(-fabsf(x)));
}
__device__ inline uint32_t packh2(float a, float b) {
  half2v h; h.x = (_Float16)a; h.y = (_Float16)b;
  return __builtin_bit_cast(uint32_t, h);
}

// ---------- prep kernels ----------
// WT16[lc][k2][g] : packed f16 pair of combined [W_ih | W_hh] row-major-in-k
__global__ void prepA(const float* __restrict__ W_ih, const float* __restrict__ W_hh,
                      uint32_t* __restrict__ WT16) {
  int idx = blockIdx.x * 256 + threadIdx.x;   // exactly 16*2*132*512
  int g  = idx & 511;
  int r  = idx >> 9;
  int k2 = r % K2N;
  int lc = r / K2N;
  int k0 = 2 * k2, k1 = k0 + 1;
  float w0 = (k0 < NN_IN) ? W_ih[((size_t)lc * G4 + g) * NN_IN + k0]
                          : W_hh[((size_t)lc * G4 + g) * H + (k0 - NN_IN)];
  float w1 = (k1 < NN_IN) ? W_ih[((size_t)lc * G4 + g) * NN_IN + k1]
                          : W_hh[((size_t)lc * G4 + g) * H + (k1 - NN_IN)];
  WT16[((size_t)lc * K2N + k2) * G4 + g] = packh2(w0, w1);
}

__global__ void prepB(const float* __restrict__ b_ih, const float* __restrict__ b_hh,
                      const float* __restrict__ W_if, const float* __restrict__ W_fri,
                      const float* __restrict__ W_c1, const float* __restrict__ W_c2,
                      float* __restrict__ bias_comb, float* __restrict__ WifT,
                      float* __restrict__ WfriT, float* __restrict__ Wc1T,
                      float* __restrict__ Wc2T) {
  int idx = blockIdx.x * 256 + threadIdx.x;
  if (idx < 16384) { bias_comb[idx] = b_ih[idx] + b_hh[idx]; return; }
  idx -= 16384;
  if (idx < 5120)  { int k = idx / 40,  j = idx % 40;  WifT[idx]  = W_if[j * 128 + k]; return; }
  idx -= 5120;
  if (idx < 81920) { int k = idx / 128, j = idx % 128; WfriT[idx] = W_fri[j * 640 + k]; return; }
  idx -= 81920;
  if (idx < 32768) { int k = idx / 128, j = idx % 128; Wc1T[idx]  = W_c1[j * 256 + k]; return; }
  idx -= 32768;
  if (idx < 3840)  { int k = idx / 30,  j = idx % 30;  Wc2T[idx]  = W_c2[j * 128 + k]; return; }
}

// ---------- memory module step (one thread per batch, DNC R=1, N=8, W=8) ----------
__device__ void memstep(const float* __restrict__ xiv, float* __restrict__ S,
                        float* __restrict__ rv_out) {
  // S: mem 0..63, link 64..127, usage 128..135, prec 136..143, rw 144..151, ww 152..159
  float xv[40];
#pragma unroll
  for (int q = 0; q < 40; q++) xv[q] = xiv[q];
  float rk[8], wk[8], er[8], wv[8];
#pragma unroll
  for (int c = 0; c < 8; c++) {
    rk[c] = tanhf(xv[c]);
    wk[c] = tanhf(xv[9 + c]);
    er[c] = sigf(xv[18 + c]);
    wv[c] = tanhf(xv[26 + c]);
  }
  float rs = softplusf(xv[8]), wsd = softplusf(xv[17]);
  float fg = sigf(xv[34]), ag = sigf(xv[35]), wg = sigf(xv[36]);
  float mmx = fmaxf(xv[37], fmaxf(xv[38], xv[39]));
  float eb = __expf(xv[37] - mmx), ef = __expf(xv[38] - mmx), ec = __expf(xv[39] - mmx);
  float minv = 1.f / (eb + ef + ec);
  float mode_b = eb * minv, mode_f = ef * minv, mode_c = ec * minv;

  float mem[64], lk[64], u[8], p[8], r[8], w[8];
#pragma unroll
  for (int i = 0; i < 64; i++) { mem[i] = S[i]; lk[i] = S[64 + i]; }
#pragma unroll
  for (int m = 0; m < 8; m++) {
    u[m] = S[128 + m]; p[m] = S[136 + m]; r[m] = S[144 + m]; w[m] = S[152 + m];
  }
  // usage update (ww_prev) then retention psi (rw_prev)
#pragma unroll
  for (int m = 0; m < 8; m++) {
    u[m] = u[m] + (1.f - u[m]) * w[m];
    u[m] *= (1.f - fg * r[m]);
  }
  // write content weights
  float kn2 = 0.f;
#pragma unroll
  for (int c = 0; c < 8; c++) kn2 += wk[c] * wk[c];
  float kinv = 1.f / (sqrtf(kn2) + EPSF);
  float wcw[8]; float smax = -1e30f;
#pragma unroll
  for (int m = 0; m < 8; m++) {
    float mn2 = 0.f, dp = 0.f;
#pragma unroll
    for (int c = 0; c < 8; c++) { float mv = mem[m * 8 + c]; mn2 += mv * mv; dp += wk[c] * mv; }
    float sim = dp * kinv / (sqrtf(mn2) + EPSF) * wsd;
    wcw[m] = sim; smax = fmaxf(smax, sim);
  }
  float ssum = 0.f;
#pragma unroll
  for (int m = 0; m < 8; m++) { wcw[m] = __expf(wcw[m] - smax); ssum += wcw[m]; }
  float sinv = 1.f / ssum;
#pragma unroll
  for (int m = 0; m < 8; m++) wcw[m] *= sinv;
  // allocation weights (stable argsort via pairwise rank)
  float up[8];
#pragma unroll
  for (int m = 0; m < 8; m++) up[m] = EPSF + (1.f - EPSF) * u[m];
  float alloc[8];
#pragma unroll
  for (int m = 0; m < 8; m++) {
    float prod = 1.f;
#pragma unroll
    for (int n = 0; n < 8; n++) {
      if (n == m) continue;
      bool before = (up[n] < up[m]) || (up[n] == up[m] && n < m);
      prod *= before ? up[n] : 1.f;
    }
    alloc[m] = (1.f - up[m]) * prod;
  }
  // new write weights
  float wn[8]; float sw = 0.f;
#pragma unroll
  for (int m = 0; m < 8; m++) { wn[m] = wg * (ag * alloc[m] + (1.f - ag) * wcw[m]); sw += wn[m]; }
  // memory write
#pragma unroll
  for (int m = 0; m < 8; m++) {
#pragma unroll
    for (int c = 0; c < 8; c++) {
      mem[m * 8 + c] = mem[m * 8 + c] * (1.f - wn[m] * er[c]) + wn[m] * wv[c];
    }
  }
  // link update (zero diagonal)
#pragma unroll
  for (int i = 0; i < 8; i++) {
#pragma unroll
    for (int j = 0; j < 8; j++) {
      lk[i * 8 + j] = (i == j) ? 0.f
                               : ((1.f - wn[i] - wn[j]) * lk[i * 8 + j] + wn[i] * p[j]);
    }
  }
  // precedence
#pragma unroll
  for (int m = 0; m < 8; m++) p[m] = (1.f - sw) * p[m] + wn[m];
  // read content weights on new mem
  float rn2 = 0.f;
#pragma unroll
  for (int c = 0; c < 8; c++) rn2 += rk[c] * rk[c];
  float rinv = 1.f / (sqrtf(rn2) + EPSF);
  float cw[8]; float rsmax = -1e30f;
#pragma unroll
  for (int m = 0; m < 8; m++) {
    float mn2 = 0.f, dp = 0.f;
#pragma unroll
    for (int c = 0; c < 8; c++) { float mv = mem[m * 8 + c]; mn2 += mv * mv; dp += rk[c] * mv; }
    float sim = dp * rinv / (sqrtf(mn2) + EPSF) * rs;
    cw[m] = sim; rsmax = fmaxf(rsmax, sim);
  }
  float rsum = 0.f;
#pragma unroll
  for (int m = 0; m < 8; m++) { cw[m] = __expf(cw[m] - rsmax); rsum += cw[m]; }
  float rsinv = 1.f / rsum;
#pragma unroll
  for (int m = 0; m < 8; m++) cw[m] *= rsinv;
  // forward / backward via link and rw_prev
  float fwd[8], bwd[8];
#pragma unroll
  for (int i = 0; i < 8; i++) {
    float a = 0.f;
#pragma unroll
    for (int j = 0; j < 8; j++) a += lk[i * 8 + j] * r[j];
    fwd[i] = a;
  }
#pragma unroll
  for (int j = 0; j < 8; j++) {
    float a = 0.f;
#pragma unroll
    for (int i = 0; i < 8; i++) a += r[i] * lk[i * 8 + j];
    bwd[j] = a;
  }
  float rn[8];
#pragma unroll
  for (int m = 0; m < 8; m++) rn[m] = mode_c * cw[m] + mode_f * fwd[m] + mode_b * bwd[m];
  // read vectors
#pragma unroll
  for (int c = 0; c < 8; c++) {
    float a = 0.f;
#pragma unroll
    for (int m = 0; m < 8; m++) a += rn[m] * mem[m * 8 + c];
    rv_out[c] = a;
  }
  // store state
#pragma unroll
  for (int i = 0; i < 64; i++) { S[i] = mem[i]; S[64 + i] = lk[i]; }
#pragma unroll
  for (int m = 0; m < 8; m++) {
    S[128 + m] = u[m]; S[136 + m] = p[m]; S[144 + m] = rn[m]; S[152 + m] = wn[m];
  }
}

// ---------- main recurrent kernel: 64 blocks x 512 threads, 2 batches/block ----------
__global__ __launch_bounds__(512) void dnc_main(
    const int* __restrict__ x, const float* __restrict__ embed,
    const uint32_t* __restrict__ WT16, const float* __restrict__ bias_comb,
    const float* __restrict__ WifT, const float* __restrict__ b_if,
    const float* __restrict__ W_out, const float* __restrict__ b_out,
    float* __restrict__ y_buf) {
  __shared__ uint16_t h_st16[LNUM * 2 * 2 * H];  // f16 bits (only consumer is f16 GEMV)
  __shared__ float    c_st[LNUM * 2 * 2 * H];    // f32 (integrates over time)
  __shared__ float    emb_lds[33 * 15];
  __shared__ float    inp[2 * NN_IN];            // [out(128) | rv(8)] per batch (f32)
  __shared__ uint32_t xcat16[K2N * 2];           // [k2][bi] packed f16 pairs
  __shared__ float    gates[2 * G4];
  __shared__ float    xi_lds[2 * 40];
  __shared__ float    mstate[2 * 160];

  const int tid = threadIdx.x;
  const int b0  = blockIdx.x * 2;

  for (int i = tid; i < LNUM * 2 * 2 * H; i += 512) { h_st16[i] = 0; c_st[i] = 0.f; }
  for (int i = tid; i < 33 * 15; i += 512) emb_lds[i] = embed[i];
  for (int i = tid; i < 2 * 160; i += 512) mstate[i] = 0.f;
  __syncthreads();

  for (int t = 0; t < TT; ++t) {
    // layer-0 input: padded embedding lookup
    if (tid < 2 * NN_IN) {
      int bi = tid / NN_IN, k = tid % NN_IN;
      int ix = x[(b0 + bi) * TT + t];
      inp[bi * NN_IN + k] = (k < 15) ? emb_lds[ix * 15 + k] : 0.f;
    }
    __syncthreads();

    for (int l = 0; l < LNUM; ++l) {
      // ---- cell0 xcat: [inp(136) | h(l,0)(128)] -> f16 pairs ----
      if (tid < 2 * K2N) {
        int bi = tid & 1, k2 = tid >> 1;
        int k0 = 2 * k2;
        uint32_t v;
        if (k0 < NN_IN) v = packh2(inp[bi * NN_IN + k0], inp[bi * NN_IN + k0 + 1]);
        else v = *(const uint32_t*)&h_st16[((l * 2 + 0) * 2 + bi) * H + (k0 - NN_IN)];
        xcat16[k2 * 2 + bi] = v;
      }
      __syncthreads();
      // ---- GEMV cell0 ----
      {
        const uint32_t* wp = WT16 + ((size_t)(l * 2 + 0) * K2N) * G4 + tid;
        float a0 = bias_comb[(l * 2 + 0) * G4 + tid], a1 = a0;
#pragma unroll 4
        for (int k2 = 0; k2 < K2N; ++k2) {
          uint32_t w = wp[(size_t)k2 * G4];
          uint2 xv = *(const uint2*)&xcat16[k2 * 2];
          a0 = fdot2(w, xv.x, a0);
          a1 = fdot2(w, xv.y, a1);
        }
        gates[tid] = a0; gates[G4 + tid] = a1;
      }
      __syncthreads();
      // ---- h0/c0 update ----
      if (tid < 256) {
        int bi = tid >> 7, j = tid & 127;
        const float* gb = gates + bi * G4;
        float gi = gb[j], gf = gb[H + j], gg = gb[2 * H + j], go = gb[3 * H + j];
        int si = ((l * 2 + 0) * 2 + bi) * H + j;
        float c2 = sigf(gf) * c_st[si] + sigf(gi) * tanhf(gg);
        c_st[si] = c2;
        float h2 = sigf(go) * tanhf(c2);
        h_st16[si] = __builtin_bit_cast(uint16_t, (_Float16)h2);
      }
      __syncthreads();
      // ---- cell1 xcat: [h0(128) | 0(8) | h(l,1)(128)] ----
      if (tid < 2 * K2N) {
        int bi = tid & 1, k2 = tid >> 1;
        int k0 = 2 * k2;
        uint32_t v;
        if (k0 < H)          v = *(const uint32_t*)&h_st16[((l * 2 + 0) * 2 + bi) * H + k0];
        else if (k0 < NN_IN) v = 0u;
        else                 v = *(const uint32_t*)&h_st16[((l * 2 + 1) * 2 + bi) * H + (k0 - NN_IN)];
        xcat16[k2 * 2 + bi] = v;
      }
      __syncthreads();
      // ---- GEMV cell1 ----
      {
        const uint32_t* wp = WT16 + ((size_t)(l * 2 + 1) * K2N) * G4 + tid;
        float a0 = bias_comb[(l * 2 + 1) * G4 + tid], a1 = a0;
#pragma unroll 4
        for (int k2 = 0; k2 < K2N; ++k2) {
          uint32_t w = wp[(size_t)k2 * G4];
          uint2 xv = *(const uint2*)&xcat16[k2 * 2];
          a0 = fdot2(w, xv.x, a0);
          a1 = fdot2(w, xv.y, a1);
        }
        gates[tid] = a0; gates[G4 + tid] = a1;
      }
      __syncthreads();
      // ---- h1/c1 update + out -> inp[0:128] ----
      if (tid < 256) {
        int bi = tid >> 7, j = tid & 127;
        const float* gb = gates + bi * G4;
        float gi = gb[j], gf = gb[H + j], gg = gb[2 * H + j], go = gb[3 * H + j];
        int si = ((l * 2 + 1) * 2 + bi) * H + j;
        float c2 = sigf(gf) * c_st[si] + sigf(gi) * tanhf(gg);
        c_st[si] = c2;
        float h2 = sigf(go) * tanhf(c2);
        h_st16[si] = __builtin_bit_cast(uint16_t, (_Float16)h2);
        inp[bi * NN_IN + j] = fminf(fmaxf(h2, -20.f), 20.f);
      }
      __syncthreads();
      // ---- xi = out @ W_if.T + b_if ----
      if (tid < 80) {
        int bi = tid / 40, j = tid % 40;
        float a = b_if[j];
        for (int k = 0; k < H; ++k) a += inp[bi * NN_IN + k] * WifT[k * 40 + j];
        xi_lds[bi * 40 + j] = a;
      }
      __syncthreads();
      // ---- DNC memory step (serial per batch) -> rv into inp[128:136] ----
      if (tid < 2) {
        memstep(xi_lds + tid * 40, mstate + tid * 160, inp + tid * NN_IN + H);
      }
      __syncthreads();
    }  // l
  }  // t

  // y = inp @ W_out.T + b_out  (t = 63 only)
  if (tid < 256) {
    int bi = tid >> 7, i = tid & 127;
    float a = b_out[i];
    for (int k = 0; k < NN_IN; ++k) a += inp[bi * NN_IN + k] * W_out[i * NN_IN + k];
    y_buf[(b0 + bi) * H + i] = a;
  }
}

// ---------- output head: 128 blocks (one per batch) x 128 threads ----------
__global__ void head_kernel(const float* __restrict__ y_buf, const float* __restrict__ f,
                            const float* __restrict__ WfriT, const float* __restrict__ b_fri,
                            const float* __restrict__ Wc1T, const float* __restrict__ b_c1,
                            const float* __restrict__ Wc2T, const float* __restrict__ b_c2,
                            float* __restrict__ out) {
  __shared__ float fl[640], yl[128], fo[128], h1l[128];
  int b = blockIdx.x, j = threadIdx.x;
  for (int i = j; i < 640; i += 128) fl[i] = f[b * 640 + i];
  yl[j] = y_buf[b * 128 + j];
  __syncthreads();
  float a = b_fri[j];
  for (int k = 0; k < 640; ++k) a += fl[k] * WfriT[k * 128 + j];
  fo[j] = fmaxf(a, 0.f);
  __syncthreads();
  float a2 = b_c1[j];
  for (int k = 0; k < 128; ++k) a2 += yl[k] * Wc1T[k * 128 + j];
  for (int k = 0; k < 128; ++k) a2 += fo[k] * Wc1T[(128 + k) * 128 + j];
  h1l[j] = fmaxf(a2, 0.f);
  __syncthreads();
  if (j < NCLSN) {
    float a3 = b_c2[j];
    for (int k = 0; k < 128; ++k) a3 += h1l[k] * Wc2T[k * NCLSN + j];
    out[b * NCLSN + j] = a3;
  }
}

extern "C" void kernel_launch(void* const* d_in, const int* in_sizes, int n_in,
                              void* d_out, int out_size, void* d_ws, size_t ws_size,
                              hipStream_t stream) {
  const int*   x     = (const int*)d_in[0];
  const float* f     = (const float*)d_in[1];
  const float* embed = (const float*)d_in[2];
  const float* W_ih  = (const float*)d_in[3];
  const float* W_hh  = (const float*)d_in[4];
  const float* b_ih  = (const float*)d_in[5];
  const float* b_hh  = (const float*)d_in[6];
  const float* W_if  = (const float*)d_in[7];
  const float* b_if  = (const float*)d_in[8];
  const float* W_out = (const float*)d_in[9];
  const float* b_out = (const float*)d_in[10];
  const float* W_fri = (const float*)d_in[11];
  const float* b_fri = (const float*)d_in[12];
  const float* W_c1  = (const float*)d_in[13];
  const float* b_c1  = (const float*)d_in[14];
  const float* W_c2  = (const float*)d_in[15];
  const float* b_c2  = (const float*)d_in[16];

  uint8_t* ws = (uint8_t*)d_ws;
  uint32_t* WT16   = (uint32_t*)(ws + 0);        // 16*2*132*512*4 = 8,650,752 B
  float* bias_comb = (float*)(ws + 8650752);     // 65,536 B
  float* WifT      = (float*)(ws + 8716288);     // 20,480 B
  float* WfriT     = (float*)(ws + 8736768);     // 327,680 B
  float* Wc1T      = (float*)(ws + 9064448);     // 131,072 B
  float* Wc2T      = (float*)(ws + 9195520);     // 15,360 B
  float* y_buf     = (float*)(ws + 9210880);     // 65,536 B
  float* out       = (float*)d_out;

  prepA<<<8448, 256, 0, stream>>>(W_ih, W_hh, WT16);
  prepB<<<547, 256, 0, stream>>>(b_ih, b_hh, W_if, W_fri, W_c1, W_c2,
                                 bias_comb, WifT, WfriT, Wc1T, Wc2T);
  dnc_main<<<64, 512, 0, stream>>>(x, embed, WT16, bias_comb, WifT, b_if,
                                   W_out, b_out, y_buf);
  head_kernel<<<128, 128, 0, stream>>>(y_buf, f, WfriT, b_fri, Wc1T, b_c1,
                                       Wc2T, b_c2, out);
}

// Round 2
// 18621.336 us; speedup vs baseline: 1.5118x; 1.5118x over previous
//
#include <hip/hip_runtime.h>
#include <stdint.h>

#define LNUM 16
#define H 128
#define G4 512
#define TT 64
#define NCLSN 30
#define EPSF 1e-6f
#define NKQ 33    // 264 f16 / 8 per uint4

typedef _Float16 half2v __attribute__((ext_vector_type(2)));

__device__ inline float fdot2(uint32_t a, uint32_t b, float c) {
  return __builtin_amdgcn_fdot2(__builtin_bit_cast(half2v, a),
                                __builtin_bit_cast(half2v, b), c, false);
}
__device__ inline float sigf(float x) { return 1.0f / (1.0f + __expf(-x)); }
__device__ inline float softplusf(float x) {
  return fmaxf(x, 0.f) + log1pf(__expf(-fabsf(x)));
}
__device__ inline uint32_t packh2(float a, float b) {
  half2v h; h.x = (_Float16)a; h.y = (_Float16)b;
  return __builtin_bit_cast(uint32_t, h);
}
__device__ inline uint16_t f16bits(float a) {
  _Float16 h = (_Float16)a;
  return __builtin_bit_cast(uint16_t, h);
}

// ---------- prep: W4[(lc*33+kq)*512+g] = 8 packed f16 of combined [W_ih|W_hh] row g ----------
__global__ void prepA(const float* __restrict__ W_ih, const float* __restrict__ W_hh,
                      uint4* __restrict__ W4) {
  int idx = blockIdx.x * 256 + threadIdx.x;   // 16*2*33*512 = 540672 = 2112*256
  int g  = idx & 511;
  int r  = idx >> 9;        // lc*33 + kq
  int kq = r % NKQ;
  int lc = r / NKQ;
  uint32_t p[4];
#pragma unroll
  for (int i = 0; i < 4; i++) {
    int k0 = 8 * kq + 2 * i, k1 = k0 + 1;
    float w0 = (k0 < 136) ? W_ih[((size_t)lc * G4 + g) * 136 + k0]
                          : W_hh[((size_t)lc * G4 + g) * H + (k0 - 136)];
    float w1 = (k1 < 136) ? W_ih[((size_t)lc * G4 + g) * 136 + k1]
                          : W_hh[((size_t)lc * G4 + g) * H + (k1 - 136)];
    p[i] = packh2(w0, w1);
  }
  uint4 v; v.x = p[0]; v.y = p[1]; v.z = p[2]; v.w = p[3];
  W4[idx] = v;
}

__global__ void prepB(const float* __restrict__ b_ih, const float* __restrict__ b_hh,
                      const float* __restrict__ W_if, const float* __restrict__ W_fri,
                      const float* __restrict__ W_c1, const float* __restrict__ W_c2,
                      float* __restrict__ bias_comb, float* __restrict__ WifT,
                      float* __restrict__ WfriT, float* __restrict__ Wc1T,
                      float* __restrict__ Wc2T) {
  int idx = blockIdx.x * 256 + threadIdx.x;
  if (idx < 16384) { bias_comb[idx] = b_ih[idx] + b_hh[idx]; return; }
  idx -= 16384;
  if (idx < 5120)  { int k = idx / 40,  j = idx % 40;  WifT[idx]  = W_if[j * 128 + k]; return; }
  idx -= 5120;
  if (idx < 81920) { int k = idx / 128, j = idx % 128; WfriT[idx] = W_fri[j * 640 + k]; return; }
  idx -= 81920;
  if (idx < 32768) { int k = idx / 128, j = idx % 128; Wc1T[idx]  = W_c1[j * 256 + k]; return; }
  idx -= 32768;
  if (idx < 3840)  { int k = idx / 30,  j = idx % 30;  Wc2T[idx]  = W_c2[j * 128 + k]; return; }
}

// ---------- memory module step (one thread per batch, DNC R=1, N=8, W=8) ----------
__device__ void memstep(const float* __restrict__ xiv, float* __restrict__ S,
                        uint16_t* __restrict__ rv16, float* __restrict__ rvf) {
  float xv[40];
#pragma unroll
  for (int q = 0; q < 40; q++) xv[q] = xiv[q];
  float rk[8], wk[8], er[8], wv[8];
#pragma unroll
  for (int c = 0; c < 8; c++) {
    rk[c] = tanhf(xv[c]);
    wk[c] = tanhf(xv[9 + c]);
    er[c] = sigf(xv[18 + c]);
    wv[c] = tanhf(xv[26 + c]);
  }
  float rs = softplusf(xv[8]), wsd = softplusf(xv[17]);
  float fg = sigf(xv[34]), ag = sigf(xv[35]), wg = sigf(xv[36]);
  float mmx = fmaxf(xv[37], fmaxf(xv[38], xv[39]));
  float eb = __expf(xv[37] - mmx), ef = __expf(xv[38] - mmx), ec = __expf(xv[39] - mmx);
  float minv = 1.f / (eb + ef + ec);
  float mode_b = eb * minv, mode_f = ef * minv, mode_c = ec * minv;

  float mem[64], lk[64], u[8], p[8], r[8], w[8];
#pragma unroll
  for (int i = 0; i < 64; i++) { mem[i] = S[i]; lk[i] = S[64 + i]; }
#pragma unroll
  for (int m = 0; m < 8; m++) {
    u[m] = S[128 + m]; p[m] = S[136 + m]; r[m] = S[144 + m]; w[m] = S[152 + m];
  }
#pragma unroll
  for (int m = 0; m < 8; m++) {
    u[m] = u[m] + (1.f - u[m]) * w[m];
    u[m] *= (1.f - fg * r[m]);
  }
  float kn2 = 0.f;
#pragma unroll
  for (int c = 0; c < 8; c++) kn2 += wk[c] * wk[c];
  float kinv = 1.f / (sqrtf(kn2) + EPSF);
  float wcw[8]; float smax = -1e30f;
#pragma unroll
  for (int m = 0; m < 8; m++) {
    float mn2 = 0.f, dp = 0.f;
#pragma unroll
    for (int c = 0; c < 8; c++) { float mv = mem[m * 8 + c]; mn2 += mv * mv; dp += wk[c] * mv; }
    float sim = dp * kinv / (sqrtf(mn2) + EPSF) * wsd;
    wcw[m] = sim; smax = fmaxf(smax, sim);
  }
  float ssum = 0.f;
#pragma unroll
  for (int m = 0; m < 8; m++) { wcw[m] = __expf(wcw[m] - smax); ssum += wcw[m]; }
  float sinv = 1.f / ssum;
#pragma unroll
  for (int m = 0; m < 8; m++) wcw[m] *= sinv;
  float up[8];
#pragma unroll
  for (int m = 0; m < 8; m++) up[m] = EPSF + (1.f - EPSF) * u[m];
  float alloc[8];
#pragma unroll
  for (int m = 0; m < 8; m++) {
    float prod = 1.f;
#pragma unroll
    for (int n = 0; n < 8; n++) {
      if (n == m) continue;
      bool before = (up[n] < up[m]) || (up[n] == up[m] && n < m);
      prod *= before ? up[n] : 1.f;
    }
    alloc[m] = (1.f - up[m]) * prod;
  }
  float wn[8]; float sw = 0.f;
#pragma unroll
  for (int m = 0; m < 8; m++) { wn[m] = wg * (ag * alloc[m] + (1.f - ag) * wcw[m]); sw += wn[m]; }
#pragma unroll
  for (int m = 0; m < 8; m++) {
#pragma unroll
    for (int c = 0; c < 8; c++) {
      mem[m * 8 + c] = mem[m * 8 + c] * (1.f - wn[m] * er[c]) + wn[m] * wv[c];
    }
  }
#pragma unroll
  for (int i = 0; i < 8; i++) {
#pragma unroll
    for (int j = 0; j < 8; j++) {
      lk[i * 8 + j] = (i == j) ? 0.f
                               : ((1.f - wn[i] - wn[j]) * lk[i * 8 + j] + wn[i] * p[j]);
    }
  }
#pragma unroll
  for (int m = 0; m < 8; m++) p[m] = (1.f - sw) * p[m] + wn[m];
  float rn2 = 0.f;
#pragma unroll
  for (int c = 0; c < 8; c++) rn2 += rk[c] * rk[c];
  float rinv = 1.f / (sqrtf(rn2) + EPSF);
  float cw[8]; float rsmax = -1e30f;
#pragma unroll
  for (int m = 0; m < 8; m++) {
    float mn2 = 0.f, dp = 0.f;
#pragma unroll
    for (int c = 0; c < 8; c++) { float mv = mem[m * 8 + c]; mn2 += mv * mv; dp += rk[c] * mv; }
    float sim = dp * rinv / (sqrtf(mn2) + EPSF) * rs;
    cw[m] = sim; rsmax = fmaxf(rsmax, sim);
  }
  float rsum = 0.f;
#pragma unroll
  for (int m = 0; m < 8; m++) { cw[m] = __expf(cw[m] - rsmax); rsum += cw[m]; }
  float rsinv = 1.f / rsum;
#pragma unroll
  for (int m = 0; m < 8; m++) cw[m] *= rsinv;
  float fwd[8], bwd[8];
#pragma unroll
  for (int i = 0; i < 8; i++) {
    float a = 0.f;
#pragma unroll
    for (int j = 0; j < 8; j++) a += lk[i * 8 + j] * r[j];
    fwd[i] = a;
  }
#pragma unroll
  for (int j = 0; j < 8; j++) {
    float a = 0.f;
#pragma unroll
    for (int i = 0; i < 8; i++) a += r[i] * lk[i * 8 + j];
    bwd[j] = a;
  }
  float rn[8];
#pragma unroll
  for (int m = 0; m < 8; m++) rn[m] = mode_c * cw[m] + mode_f * fwd[m] + mode_b * bwd[m];
#pragma unroll
  for (int c = 0; c < 8; c++) {
    float a = 0.f;
#pragma unroll
    for (int m = 0; m < 8; m++) a += rn[m] * mem[m * 8 + c];
    rv16[c] = f16bits(a);
    rvf[c] = a;
  }
#pragma unroll
  for (int i = 0; i < 64; i++) { S[i] = mem[i]; S[64 + i] = lk[i]; }
#pragma unroll
  for (int m = 0; m < 8; m++) {
    S[128 + m] = u[m]; S[136 + m] = p[m]; S[144 + m] = rn[m]; S[152 + m] = wn[m];
  }
}

// ---------- main recurrent kernel: 64 blocks x 512 threads, 2 batches/block ----------
__global__ __launch_bounds__(512) void dnc_main(
    const int* __restrict__ x, const float* __restrict__ embed,
    const uint4* __restrict__ W4, const float* __restrict__ bias_comb,
    const float* __restrict__ WifT, const float* __restrict__ b_if,
    const float* __restrict__ W_out, const float* __restrict__ b_out,
    float* __restrict__ y_buf) {
  __shared__ __align__(16) uint16_t h_st16[LNUM * 2 * 2 * H];  // f16 h-state
  __shared__ float    c_st[LNUM * 2 * 2 * H];                  // f32 c-state
  __shared__ float    emb_lds[33 * 15];
  __shared__ float    inp_f32[2 * H];        // clipped h1 (layer output), f32 for xi / y
  __shared__ __align__(16) uint32_t inp16[2 * 68];  // layer input as packed f16 (136 vals + rv)
  __shared__ float    gates[2 * G4];
  __shared__ float    xi_lds[80];
  __shared__ float    rv_f32[16];
  __shared__ float    mstate[2 * 160];

  const int tid = threadIdx.x;
  const int b0  = blockIdx.x * 2;

  for (int i = tid; i < LNUM * 2 * 2 * H; i += 512) { h_st16[i] = 0; c_st[i] = 0.f; }
  for (int i = tid; i < 33 * 15; i += 512) emb_lds[i] = embed[i];
  for (int i = tid; i < 2 * 160; i += 512) mstate[i] = 0.f;
  __syncthreads();

  for (int t = 0; t < TT; ++t) {
    // layer-0 input: padded embedding lookup -> packed f16
    if (tid < 2 * 68) {
      int bi = tid / 68, q = tid % 68;
      int ix = x[(b0 + bi) * TT + t];
      int k0 = 2 * q, k1 = k0 + 1;
      float e0 = (k0 < 15) ? emb_lds[ix * 15 + k0] : 0.f;
      float e1 = (k1 < 15) ? emb_lds[ix * 15 + k1] : 0.f;
      inp16[bi * 68 + q] = packh2(e0, e1);
    }
    __syncthreads();

    for (int l = 0; l < LNUM; ++l) {
      // ---- GEMV cell0: x = [inp16(136 incl rv)] ++ h_st16[l,0] ----
      {
        const uint4* __restrict__ wp = W4 + (size_t)(l * 2 + 0) * NKQ * G4 + tid;
        const uint4* xA = (const uint4*)inp16;
        const uint4* xB = (const uint4*)(inp16 + 68);
        const uint4* hA = (const uint4*)(h_st16 + ((l * 2 + 0) * 2 + 0) * H);
        const uint4* hB = (const uint4*)(h_st16 + ((l * 2 + 0) * 2 + 1) * H);
        float a0 = bias_comb[(l * 2 + 0) * G4 + tid], a1 = a0;
        float e0 = 0.f, e1 = 0.f;
#pragma unroll
        for (int kq = 0; kq < 17; ++kq) {
          uint4 w = wp[kq * G4];
          uint4 x0 = xA[kq], x1 = xB[kq];
          a0 = fdot2(w.x, x0.x, a0); a0 = fdot2(w.y, x0.y, a0);
          a0 = fdot2(w.z, x0.z, a0); a0 = fdot2(w.w, x0.w, a0);
          a1 = fdot2(w.x, x1.x, a1); a1 = fdot2(w.y, x1.y, a1);
          a1 = fdot2(w.z, x1.z, a1); a1 = fdot2(w.w, x1.w, a1);
        }
#pragma unroll
        for (int kq = 17; kq < 33; ++kq) {
          uint4 w = wp[kq * G4];
          uint4 x0 = hA[kq - 17], x1 = hB[kq - 17];
          e0 = fdot2(w.x, x0.x, e0); e0 = fdot2(w.y, x0.y, e0);
          e0 = fdot2(w.z, x0.z, e0); e0 = fdot2(w.w, x0.w, e0);
          e1 = fdot2(w.x, x1.x, e1); e1 = fdot2(w.y, x1.y, e1);
          e1 = fdot2(w.z, x1.z, e1); e1 = fdot2(w.w, x1.w, e1);
        }
        gates[tid] = a0 + e0; gates[G4 + tid] = a1 + e1;
      }
      __syncthreads();
      // ---- h0/c0 update ----
      if (tid < 256) {
        int bi = tid >> 7, j = tid & 127;
        const float* gb = gates + bi * G4;
        float gi = gb[j], gf = gb[H + j], gg = gb[2 * H + j], go = gb[3 * H + j];
        int si = ((l * 2 + 0) * 2 + bi) * H + j;
        float c2 = sigf(gf) * c_st[si] + sigf(gi) * tanhf(gg);
        c_st[si] = c2;
        h_st16[si] = f16bits(sigf(go) * tanhf(c2));
      }
      __syncthreads();
      // ---- GEMV cell1: x = [h0(128), pad(8)=skip] ++ h_st16[l,1] ----
      {
        const uint4* __restrict__ wp = W4 + (size_t)(l * 2 + 1) * NKQ * G4 + tid;
        const uint4* xA = (const uint4*)(h_st16 + ((l * 2 + 0) * 2 + 0) * H);
        const uint4* xB = (const uint4*)(h_st16 + ((l * 2 + 0) * 2 + 1) * H);
        const uint4* hA = (const uint4*)(h_st16 + ((l * 2 + 1) * 2 + 0) * H);
        const uint4* hB = (const uint4*)(h_st16 + ((l * 2 + 1) * 2 + 1) * H);
        float a0 = bias_comb[(l * 2 + 1) * G4 + tid], a1 = a0;
        float e0 = 0.f, e1 = 0.f;
#pragma unroll
        for (int kq = 0; kq < 16; ++kq) {       // k 0..127 (h0); kq16 = zero pad, skipped
          uint4 w = wp[kq * G4];
          uint4 x0 = xA[kq], x1 = xB[kq];
          a0 = fdot2(w.x, x0.x, a0); a0 = fdot2(w.y, x0.y, a0);
          a0 = fdot2(w.z, x0.z, a0); a0 = fdot2(w.w, x0.w, a0);
          a1 = fdot2(w.x, x1.x, a1); a1 = fdot2(w.y, x1.y, a1);
          a1 = fdot2(w.z, x1.z, a1); a1 = fdot2(w.w, x1.w, a1);
        }
#pragma unroll
        for (int kq = 17; kq < 33; ++kq) {      // k 136..263 (h1 prev)
          uint4 w = wp[kq * G4];
          uint4 x0 = hA[kq - 17], x1 = hB[kq - 17];
          e0 = fdot2(w.x, x0.x, e0); e0 = fdot2(w.y, x0.y, e0);
          e0 = fdot2(w.z, x0.z, e0); e0 = fdot2(w.w, x0.w, e0);
          e1 = fdot2(w.x, x1.x, e1); e1 = fdot2(w.y, x1.y, e1);
          e1 = fdot2(w.z, x1.z, e1); e1 = fdot2(w.w, x1.w, e1);
        }
        gates[tid] = a0 + e0; gates[G4 + tid] = a1 + e1;
      }
      __syncthreads();
      // ---- h1/c1 update + layer output ----
      if (tid < 256) {
        int bi = tid >> 7, j = tid & 127;
        const float* gb = gates + bi * G4;
        float gi = gb[j], gf = gb[H + j], gg = gb[2 * H + j], go = gb[3 * H + j];
        int si = ((l * 2 + 1) * 2 + bi) * H + j;
        float c2 = sigf(gf) * c_st[si] + sigf(gi) * tanhf(gg);
        c_st[si] = c2;
        float h2 = sigf(go) * tanhf(c2);   // |h2|<1 so clip(+-20) is a no-op
        h_st16[si] = f16bits(h2);
        inp_f32[bi * H + j] = h2;
        ((uint16_t*)inp16)[bi * 136 + j] = f16bits(h2);
      }
      __syncthreads();
      // ---- xi = out @ W_if.T + b_if : 5 waves, 4-way k-split + shfl reduce ----
      if (tid < 320) {
        int w = tid >> 6, lane = tid & 63;
        int o = w * 16 + (lane & 15);       // 0..79
        int s = lane >> 4;                  // k-slice 0..3
        int bi = o >= 40, j = o - 40 * bi;
        float acc = 0.f;
        const float* ip = inp_f32 + bi * H + s * 32;
        const float* wq = WifT + (s * 32) * 40 + j;
#pragma unroll 8
        for (int i = 0; i < 32; ++i) acc += ip[i] * wq[i * 40];
        acc += __shfl_xor(acc, 16);
        acc += __shfl_xor(acc, 32);
        if (s == 0) xi_lds[o] = acc + b_if[j];
      }
      __syncthreads();
      // ---- DNC memory step (serial per batch) -> rv into inp16 tail ----
      if (tid < 2) {
        memstep(xi_lds + tid * 40, mstate + tid * 160,
                ((uint16_t*)inp16) + tid * 136 + 128, rv_f32 + tid * 8);
      }
      __syncthreads();
    }  // l
  }  // t

  // y = inp @ W_out.T + b_out  (t = 63 only)
  if (tid < 256) {
    int bi = tid >> 7, i = tid & 127;
    float a = b_out[i];
    for (int k = 0; k < H; ++k)  a += inp_f32[bi * H + k] * W_out[i * 136 + k];
    for (int k = 0; k < 8; ++k)  a += rv_f32[bi * 8 + k] * W_out[i * 136 + 128 + k];
    y_buf[(b0 + bi) * H + i] = a;
  }
}

// ---------- output head: 128 blocks (one per batch) x 128 threads ----------
__global__ void head_kernel(const float* __restrict__ y_buf, const float* __restrict__ f,
                            const float* __restrict__ WfriT, const float* __restrict__ b_fri,
                            const float* __restrict__ Wc1T, const float* __restrict__ b_c1,
                            const float* __restrict__ Wc2T, const float* __restrict__ b_c2,
                            float* __restrict__ out) {
  __shared__ float fl[640], yl[128], fo[128], h1l[128];
  int b = blockIdx.x, j = threadIdx.x;
  for (int i = j; i < 640; i += 128) fl[i] = f[b * 640 + i];
  yl[j] = y_buf[b * 128 + j];
  __syncthreads();
  float a = b_fri[j];
  for (int k = 0; k < 640; ++k) a += fl[k] * WfriT[k * 128 + j];
  fo[j] = fmaxf(a, 0.f);
  __syncthreads();
  float a2 = b_c1[j];
  for (int k = 0; k < 128; ++k) a2 += yl[k] * Wc1T[k * 128 + j];
  for (int k = 0; k < 128; ++k) a2 += fo[k] * Wc1T[(128 + k) * 128 + j];
  h1l[j] = fmaxf(a2, 0.f);
  __syncthreads();
  if (j < NCLSN) {
    float a3 = b_c2[j];
    for (int k = 0; k < 128; ++k) a3 += h1l[k] * Wc2T[k * NCLSN + j];
    out[b * NCLSN + j] = a3;
  }
}

extern "C" void kernel_launch(void* const* d_in, const int* in_sizes, int n_in,
                              void* d_out, int out_size, void* d_ws, size_t ws_size,
                              hipStream_t stream) {
  const int*   x     = (const int*)d_in[0];
  const float* f     = (const float*)d_in[1];
  const float* embed = (const float*)d_in[2];
  const float* W_ih  = (const float*)d_in[3];
  const float* W_hh  = (const float*)d_in[4];
  const float* b_ih  = (const float*)d_in[5];
  const float* b_hh  = (const float*)d_in[6];
  const float* W_if  = (const float*)d_in[7];
  const float* b_if  = (const float*)d_in[8];
  const float* W_out = (const float*)d_in[9];
  const float* b_out = (const float*)d_in[10];
  const float* W_fri = (const float*)d_in[11];
  const float* b_fri = (const float*)d_in[12];
  const float* W_c1  = (const float*)d_in[13];
  const float* b_c1  = (const float*)d_in[14];
  const float* W_c2  = (const float*)d_in[15];
  const float* b_c2  = (const float*)d_in[16];

  uint8_t* ws = (uint8_t*)d_ws;
  uint4* W4        = (uint4*)(ws + 0);           // 540672*16 = 8,650,752 B
  float* bias_comb = (float*)(ws + 8650752);     // 65,536 B
  float* WifT      = (float*)(ws + 8716288);     // 20,480 B
  float* WfriT     = (float*)(ws + 8736768);     // 327,680 B
  float* Wc1T      = (float*)(ws + 9064448);     // 131,072 B
  float* Wc2T      = (float*)(ws + 9195520);     // 15,360 B
  float* y_buf     = (float*)(ws + 9210880);     // 65,536 B
  float* out       = (float*)d_out;

  prepA<<<2112, 256, 0, stream>>>(W_ih, W_hh, W4);
  prepB<<<547, 256, 0, stream>>>(b_ih, b_hh, W_if, W_fri, W_c1, W_c2,
                                 bias_comb, WifT, WfriT, Wc1T, Wc2T);
  dnc_main<<<64, 512, 0, stream>>>(x, embed, W4, bias_comb, WifT, b_if,
                                   W_out, b_out, y_buf);
  head_kernel<<<128, 128, 0, stream>>>(y_buf, f, WfriT, b_fri, Wc1T, b_c1,
                                       Wc2T, b_c2, out);
}